// Round 18
// baseline (116.006 us; speedup 1.0000x reference)
//
#include <hip/hip_runtime.h>

#define IND 256
#define KC  64   // k per chunk; 4 chunks; dbuf = 2*(KC/2)*256*4 = 65,536 B (proven R17)

__global__ __launch_bounds__(512, 1)
void FeatureEncodingLayer_30374008718005_kernel(
        const float* __restrict__ X,      // [1024][256]
        const float* __restrict__ W,      // [4096][256]
        const float* __restrict__ bias,   // [4096]
        float* __restrict__ outf)         // [1024][4][4][2048] float32 = Re(kron)
{
    // Pair-interleaved, XOR-swizzled: word (kp, u, k&1) at Ws[buf][kp][(2u+(k&1)) ^ ((kp&7)<<2)].
    // Lane's ds_read_b128 at (4*lane)^sw -> units 2lane,2lane+1 x 2 k's, conflict-free.
    __shared__ float Ws[2][KC / 2][256];

    const int tid  = threadIdx.x;
    const int lane = tid & 63;
    const int wid  = __builtin_amdgcn_readfirstlane(tid >> 6);  // wave 0..7

    const int ut = blockIdx.x & 31;    // 32 unit tiles x 128 units
    const int bt = blockIdx.x >> 5;    // 8 batch tiles x 128 batches
    const int b0 = bt * 128 + 16 * wid;   // wave's 16 batches
    const int u0 = ut * 128;
    const int p0 = ut * 64;

    const int q  = tid & 15;           // k-quad: local k = 4q..4q+3
    const int rq = tid >> 4;           // 0..31

    const float* xc = X + (size_t)b0 * IND;   // wave-uniform -> scalar loads

    float acc[16][2];
#pragma unroll
    for (int i = 0; i < 16; ++i) { acc[i][0] = 0.f; acc[i][1] = 0.f; }

    float4 pf[4];
#define STAGE_LOAD(c) do {                                                     \
    _Pragma("unroll")                                                          \
    for (int j = 0; j < 4; ++j)                                                \
        pf[j] = *reinterpret_cast<const float4*>(                              \
            W + (size_t)(u0 + rq + 32 * j) * IND + (c) * KC + q * 4);          \
    } while (0)

#define STAGE_WRITE(buf) do {                                                  \
    const int kp0 = 2 * q, kp1 = 2 * q + 1;                                    \
    const int sw0 = (kp0 & 7) << 2, sw1 = (kp1 & 7) << 2;                      \
    _Pragma("unroll")                                                          \
    for (int j = 0; j < 4; ++j) {                                              \
        const int u2 = 2 * (rq + 32 * j);                                      \
        *reinterpret_cast<float2*>(&Ws[buf][kp0][u2 ^ sw0]) =                  \
            make_float2(pf[j].x, pf[j].y);                                     \
        *reinterpret_cast<float2*>(&Ws[buf][kp1][u2 ^ sw1]) =                  \
            make_float2(pf[j].z, pf[j].w);                                     \
    }                                                                          \
    } while (0)

    // per t: 2 conflict-free b128 reads feed 16 batches x 2 units x 4 k = 128 FMA
#define COMPUTE(buf, c) do {                                                   \
    _Pragma("unroll")                                                          \
    for (int t = 0; t < 16; ++t) {                                             \
        const int sw0 = ((2 * t) & 7) << 2, sw1 = ((2 * t + 1) & 7) << 2;      \
        const float4 w0 = *reinterpret_cast<const float4*>(                    \
            &Ws[buf][2 * t][(4 * lane) ^ sw0]);                                \
        const float4 w1 = *reinterpret_cast<const float4*>(                    \
            &Ws[buf][2 * t + 1][(4 * lane) ^ sw1]);                            \
        _Pragma("unroll")                                                      \
        for (int i = 0; i < 16; ++i) {                                         \
            const float4 xv = *reinterpret_cast<const float4*>(                \
                xc + i * IND + (c) * KC + 4 * t);                              \
            acc[i][0] = fmaf(xv.x, w0.x, acc[i][0]);                           \
            acc[i][0] = fmaf(xv.y, w0.y, acc[i][0]);                           \
            acc[i][1] = fmaf(xv.x, w0.z, acc[i][1]);                           \
            acc[i][1] = fmaf(xv.y, w0.w, acc[i][1]);                           \
            acc[i][0] = fmaf(xv.z, w1.x, acc[i][0]);                           \
            acc[i][0] = fmaf(xv.w, w1.y, acc[i][0]);                           \
            acc[i][1] = fmaf(xv.z, w1.z, acc[i][1]);                           \
            acc[i][1] = fmaf(xv.w, w1.w, acc[i][1]);                           \
        }                                                                      \
    }                                                                          \
    } while (0)

    STAGE_LOAD(0); STAGE_WRITE(0); __syncthreads();
    STAGE_LOAD(1); COMPUTE(0, 0); STAGE_WRITE(1); __syncthreads();
    STAGE_LOAD(2); COMPUTE(1, 1); STAGE_WRITE(0); __syncthreads();
    STAGE_LOAD(3); COMPUTE(0, 2); STAGE_WRITE(1); __syncthreads();

    // ---- zero-slot stores (67 MB chip-wide): issued after the LAST barrier, so
    // no vmcnt(0) ever drains them; they ride out under the final chunk's FMA
    // (lgkmcnt-only waits) + epilogue trig, overlapping the store tail.
#pragma unroll
    for (int i = 0; i < 16; ++i) {
        float* zb = outf + (size_t)(b0 + i) * 32768 + p0 + lane;
        zb[ 1 * 2048] = 0.f; zb[ 2 * 2048] = 0.f;
        zb[ 4 * 2048] = 0.f; zb[ 7 * 2048] = 0.f;
        zb[ 8 * 2048] = 0.f; zb[11 * 2048] = 0.f;
        zb[13 * 2048] = 0.f; zb[14 * 2048] = 0.f;
    }

    COMPUTE(1, 3);
#undef STAGE_LOAD
#undef STAGE_WRITE
#undef COMPUTE

    // ---- epilogue: lane owns pair p0+lane (units u0+2lane, +1), 16 batches ----
    const float2 bv = *reinterpret_cast<const float2*>(bias + u0 + 2 * lane);

#pragma unroll
    for (int i = 0; i < 16; ++i) {
        const float tA = acc[i][0] + bv.x;
        const float tB = acc[i][1] + bv.y;
        float sA, cA, sB, cB;
        __sincosf(tA, &sA, &cA);
        __sincosf(tB, &sB, &cB);
        const float ca = 0.5f * (1.f + cA);   // cos^2(tA/2)
        const float sa = 0.5f * (1.f - cA);   // sin^2(tA/2)
        const float cb = 0.5f * (1.f + cB);
        const float sb = 0.5f * (1.f - cB);
        const float oo = 0.25f * sA * sB;     // sin(tA)/2 * sin(tB)/2

        float* bp = outf + (size_t)(b0 + i) * 32768 + p0 + lane;
        bp[ 0 * 2048] =  ca * cb;
        bp[ 3 * 2048] = -oo;
        bp[ 5 * 2048] =  ca * sb;
        bp[ 6 * 2048] =  oo;
        bp[ 9 * 2048] =  oo;
        bp[10 * 2048] =  sa * cb;
        bp[12 * 2048] = -oo;
        bp[15 * 2048] =  sa * sb;
    }
}

extern "C" void kernel_launch(void* const* d_in, const int* in_sizes, int n_in,
                              void* d_out, int out_size, void* d_ws, size_t ws_size,
                              hipStream_t stream) {
    const float* X  = (const float*)d_in[0];
    const float* W  = (const float*)d_in[1];
    const float* bv = (const float*)d_in[2];

    // 8 batch-tiles x 32 unit-tiles = 256 blocks x 512 threads (~1 block/CU,
    // 8 waves). Each b128 LDS read feeds 64 FMA -> LDS pipe 4x under VALU.
    FeatureEncodingLayer_30374008718005_kernel<<<dim3(256), dim3(512), 0, stream>>>(
        X, W, bv, (float*)d_out);
}

// Round 19
// 55.918 us; speedup vs baseline: 2.0746x; 2.0746x over previous
//
#include <hip/hip_runtime.h>

#define IND 256

__global__ __launch_bounds__(256, 2)
void FeatureEncodingLayer_30374008718005_kernel(
        const float* __restrict__ X,      // [1024][256]
        const float* __restrict__ W,      // [4096][256]
        const float* __restrict__ bias,   // [4096]
        float* __restrict__ outf)         // [1024][4][4][2048] float32 = Re(kron)
{
    // One 64KB half-K W tile: Ws[kk][u ^ ((kk>>2 & 7)<<2)] (mask mult-of-4 keeps
    // b64 unit-pairs adjacent & aligned). Read: whole 512B row per instr,
    // bijective permute -> bandwidth-optimal, no hot banks. Staged TWICE total.
    __shared__ float Ws[128][128];

    const int tid  = threadIdx.x;
    const int lane = tid & 63;
    const int wid  = __builtin_amdgcn_readfirstlane(tid >> 6);  // wave 0..3

    const int ut = blockIdx.x & 31;      // 32 unit tiles x 128 units
    const int bt = blockIdx.x >> 5;      // 16 batch tiles x 64 batches
    const int b0 = bt * 64 + 16 * wid;   // wave's 16 batches (wave-uniform)
    const int u0 = ut * 128;
    const int p0 = ut * 64;

    // staging roles: k-major for perfect global coalescing
    const int k4 = tid & 31;             // float4 index within 128-k half
    const int ur = tid >> 5;             // row base 0..7

    const float* xc = X + (size_t)b0 * IND;   // wave-uniform -> s_load

    float acc[16][2];
#pragma unroll
    for (int i = 0; i < 16; ++i) { acc[i][0] = 0.f; acc[i][1] = 0.f; }

#pragma unroll
    for (int st = 0; st < 2; ++st) {
        if (st) __syncthreads();         // readers done with buffer (drains no stores:
                                         // none issued yet at this point)
        // ---- stage half-K: 128 u x 128 k, two 8-float4 sub-passes ----
#pragma unroll
        for (int sp = 0; sp < 2; ++sp) {
            float4 pf[8];
#pragma unroll
            for (int j = 0; j < 8; ++j) {
                const int u = ur + 8 * (sp * 8 + j);
                pf[j] = *reinterpret_cast<const float4*>(
                    W + (size_t)(u0 + u) * IND + st * 128 + 4 * k4);
            }
            const int m = (k4 & 7) << 2;
#pragma unroll
            for (int j = 0; j < 8; ++j) {
                const int col = (ur + 8 * (sp * 8 + j)) ^ m;
                Ws[4 * k4 + 0][col] = pf[j].x;
                Ws[4 * k4 + 1][col] = pf[j].y;
                Ws[4 * k4 + 2][col] = pf[j].z;
                Ws[4 * k4 + 3][col] = pf[j].w;
            }
        }
        __syncthreads();                 // buffer ready (drains stage reads only)

        if (st == 1) {
            // ---- zero-slot stores (half the output, data-independent): issued
            // after the LAST barrier of the kernel -> no vmcnt(0) ever drains
            // them; they ride out under compute-half-2 + epilogue.
#pragma unroll
            for (int i = 0; i < 16; ++i) {
                float* zb = outf + (size_t)(b0 + i) * 32768 + p0 + lane;
                zb[ 1 * 2048] = 0.f; zb[ 2 * 2048] = 0.f;
                zb[ 4 * 2048] = 0.f; zb[ 7 * 2048] = 0.f;
                zb[ 8 * 2048] = 0.f; zb[11 * 2048] = 0.f;
                zb[13 * 2048] = 0.f; zb[14 * 2048] = 0.f;
            }
        }

        // ---- barrier-free compute half: per k, 1 ds_read_b64 + 32 FMA ----
#pragma unroll 4
        for (int kk = 0; kk < 128; ++kk) {
            const int mm = ((kk >> 2) & 7) << 2;
            const float2 wv = *reinterpret_cast<const float2*>(
                &Ws[kk][(2 * lane) ^ mm]);        // units 2*lane, 2*lane+1
            const int kg = st * 128 + kk;
#pragma unroll
            for (int i = 0; i < 16; ++i) {
                const float xv = xc[i * IND + kg];    // wave-uniform -> s_load
                acc[i][0] = fmaf(xv, wv.x, acc[i][0]);
                acc[i][1] = fmaf(xv, wv.y, acc[i][1]);
            }
        }
    }

    // ---- epilogue: lane owns pair p0+lane (units u0+2lane, +1), 16 batches ----
    const float2 bv = *reinterpret_cast<const float2*>(bias + u0 + 2 * lane);

#pragma unroll
    for (int i = 0; i < 16; ++i) {
        const float tA = acc[i][0] + bv.x;
        const float tB = acc[i][1] + bv.y;
        float sA, cA, sB, cB;
        __sincosf(tA, &sA, &cA);
        __sincosf(tB, &sB, &cB);
        const float ca = 0.5f * (1.f + cA);   // cos^2(tA/2)
        const float sa = 0.5f * (1.f - cA);   // sin^2(tA/2)
        const float cb = 0.5f * (1.f + cB);
        const float sb = 0.5f * (1.f - cB);
        const float oo = 0.25f * sA * sB;     // sin(tA)/2 * sin(tB)/2

        float* bp = outf + (size_t)(b0 + i) * 32768 + p0 + lane;
        bp[ 0 * 2048] =  ca * cb;
        bp[ 3 * 2048] = -oo;
        bp[ 5 * 2048] =  ca * sb;
        bp[ 6 * 2048] =  oo;
        bp[ 9 * 2048] =  oo;
        bp[10 * 2048] =  sa * cb;
        bp[12 * 2048] = -oo;
        bp[15 * 2048] =  sa * sb;
    }
}

extern "C" void kernel_launch(void* const* d_in, const int* in_sizes, int n_in,
                              void* d_out, int out_size, void* d_ws, size_t ws_size,
                              hipStream_t stream) {
    const float* X  = (const float*)d_in[0];
    const float* W  = (const float*)d_in[1];
    const float* bv = (const float*)d_in[2];

    // 16 batch-tiles x 32 unit-tiles = 512 blocks x 256 threads; 64KB LDS
    // -> 2 blocks/CU, 8 waves/CU. Only 3 barriers in the entire kernel.
    FeatureEncodingLayer_30374008718005_kernel<<<dim3(512), dim3(256), 0, stream>>>(
        X, W, bv, (float*)d_out);
}

// Round 20
// 44.183 us; speedup vs baseline: 2.6256x; 1.2656x over previous
//
#include <hip/hip_runtime.h>

#define IND 256
#define KC  32

__global__ __launch_bounds__(256, 4)
void FeatureEncodingLayer_30374008718005_kernel(
        const float* __restrict__ X,      // [1024][256]
        const float* __restrict__ W,      // [4096][256]
        const float* __restrict__ bias,   // [4096]
        float* __restrict__ outf)         // [1024][4][4][2048] float32 = Re(kron)
{
    // Pair-interleaved, XOR-swizzled W tile (layout verified in R17):
    // word (kp, u, k&1) at Ws[buf][kp][(2u+(k&1)) ^ ((kp&7)<<2)], kp = k>>1.
    // Lane's ds_read_b128 covers its unit-pair x 2 k's; lanes 0..7 span words
    // 0..31 of a row -> conflict-free full-bandwidth rows.
    __shared__ float Ws[2][KC / 2][256];   // 32 KB

    const int tid  = threadIdx.x;
    const int lane = tid & 63;
    const int wid  = __builtin_amdgcn_readfirstlane(tid >> 6);  // wave 0..3

    const int ut = blockIdx.x & 31;    // 32 unit tiles x 128 units
    const int bt = blockIdx.x >> 5;    // 32 batch tiles x 32 batches
    const int b0 = bt * 32;
    const int u0 = ut * 128;
    const int p0 = ut * 64;

    const int q  = tid & 7;            // k-quad: local k = 4q..4q+3
    const int rq = tid >> 3;           // row subgroup 0..31

    const float* xc = X + (size_t)(b0 + 8 * wid) * IND;  // wave-uniform -> s_load

    float acc[8][2];
#pragma unroll
    for (int i = 0; i < 8; ++i) { acc[i][0] = 0.f; acc[i][1] = 0.f; }

    float4 pf[4];
#define STAGE_LOAD(c) do {                                                     \
    _Pragma("unroll")                                                          \
    for (int j = 0; j < 4; ++j)                                                \
        pf[j] = *reinterpret_cast<const float4*>(                              \
            W + (size_t)(u0 + rq + 32 * j) * IND + (c) * KC + q * 4);          \
    } while (0)

#define STAGE_WRITE(buf) do {                                                  \
    const int kp0 = 2 * q, kp1 = 2 * q + 1;                                    \
    const int sw0 = (kp0 & 7) << 2, sw1 = (kp1 & 7) << 2;                      \
    _Pragma("unroll")                                                          \
    for (int j = 0; j < 4; ++j) {                                              \
        const int u2 = 2 * (rq + 32 * j);                                      \
        *reinterpret_cast<float2*>(&Ws[buf][kp0][u2 ^ sw0]) =                  \
            make_float2(pf[j].x, pf[j].y);                                     \
        *reinterpret_cast<float2*>(&Ws[buf][kp1][u2 ^ sw1]) =                  \
            make_float2(pf[j].z, pf[j].w);                                     \
    }                                                                          \
    } while (0)

    // LDS-only barrier: lgkmcnt(0) makes ds_writes/ds_reads visible, but global
    // stores stay IN FLIGHT across it (unlike __syncthreads' vmcnt(0) drain --
    // the exact mechanism that sank R15's zero-store hiding).
#define LDS_BARRIER() do {                                                     \
    asm volatile("s_waitcnt lgkmcnt(0)" ::: "memory");                         \
    __builtin_amdgcn_s_barrier();                                              \
    } while (0)

    STAGE_LOAD(0);
    STAGE_WRITE(0);
    LDS_BARRIER();

    for (int c = 0; c < IND / KC; ++c) {
        const int cur = c & 1;
        if (c < IND / KC - 1) STAGE_LOAD(c + 1);   // prefetch (no wait yet)

        // ---- zero-slot stores (67 MB chip-wide = half the output), one slot
        // per chunk, issued AFTER the prefetch loads; never drained by barriers.
        {
            const int zrc = (int)((0xEDB87421u >> (4 * c)) & 0xFu);
            float* zp = outf + (size_t)(b0 + 8 * wid) * 32768
                       + (size_t)zrc * 2048 + p0 + lane;
#pragma unroll
            for (int i = 0; i < 8; ++i)
                zp[(size_t)i * 32768] = 0.f;       // coalesced 256B per wave
        }

        // ---- compute: per kp, 1 conflict-free ds_read_b128 + 32 FMA ----
#pragma unroll 8
        for (int kp = 0; kp < KC / 2; ++kp) {
            const int sw = (kp & 7) << 2;
            const float4 wq = *reinterpret_cast<const float4*>(
                &Ws[cur][kp][(4 * lane) ^ sw]);
            // wq = {W[2l][2kp], W[2l][2kp+1], W[2l+1][2kp], W[2l+1][2kp+1]}
            const int kg = c * KC + 2 * kp;
#pragma unroll
            for (int i = 0; i < 8; ++i) {
                const float x0 = xc[i * IND + kg];      // wave-uniform s_load
                const float x1 = xc[i * IND + kg + 1];
                acc[i][0] = fmaf(x0, wq.x, acc[i][0]);
                acc[i][0] = fmaf(x1, wq.y, acc[i][0]);
                acc[i][1] = fmaf(x0, wq.z, acc[i][1]);
                acc[i][1] = fmaf(x1, wq.w, acc[i][1]);
            }
        }
        if (c < IND / KC - 1) {
            STAGE_WRITE(cur ^ 1);                  // vmcnt wait: only its loads
            LDS_BARRIER();
        }
    }
#undef STAGE_LOAD
#undef STAGE_WRITE
#undef LDS_BARRIER

    // ---- epilogue: lane owns pair p0+lane (units u0+2lane, +1), 8 batches;
    // only the 8 nonzero slots remain (zeros already in flight).
    const float2 bv = *reinterpret_cast<const float2*>(bias + u0 + 2 * lane);

#pragma unroll
    for (int i = 0; i < 8; ++i) {
        const int b = b0 + 8 * wid + i;
        const float tA = acc[i][0] + bv.x;
        const float tB = acc[i][1] + bv.y;
        float sA, cA, sB, cB;
        __sincosf(tA, &sA, &cA);
        __sincosf(tB, &sB, &cB);
        const float ca = 0.5f * (1.f + cA);   // cos^2(tA/2)
        const float sa = 0.5f * (1.f - cA);   // sin^2(tA/2)
        const float cb = 0.5f * (1.f + cB);
        const float sb = 0.5f * (1.f - cB);
        const float oo = 0.25f * sA * sB;     // sin(tA)/2 * sin(tB)/2

        float* bp = outf + (size_t)b * 32768 + p0 + lane;
        bp[ 0 * 2048] =  ca * cb;
        bp[ 3 * 2048] = -oo;
        bp[ 5 * 2048] =  ca * sb;
        bp[ 6 * 2048] =  oo;
        bp[ 9 * 2048] =  oo;
        bp[10 * 2048] =  sa * cb;
        bp[12 * 2048] = -oo;
        bp[15 * 2048] =  sa * sb;
    }
}

extern "C" void kernel_launch(void* const* d_in, const int* in_sizes, int n_in,
                              void* d_out, int out_size, void* d_ws, size_t ws_size,
                              hipStream_t stream) {
    const float* X  = (const float*)d_in[0];
    const float* W  = (const float*)d_in[1];
    const float* bv = (const float*)d_in[2];

    // R14's proven shape: 32 bt x 32 ut = 1024 blocks, 256 threads, 4 blocks/CU.
    FeatureEncodingLayer_30374008718005_kernel<<<dim3(1024), dim3(256), 0, stream>>>(
        X, W, bv, (float*)d_out);
}